// Round 3
// baseline (646.110 us; speedup 1.0000x reference)
//
#include <hip/hip_runtime.h>
#include <hip/hip_bf16.h>

#define EPS_F 1e-12f

typedef __attribute__((ext_vector_type(8))) short bf16x8;
typedef __attribute__((ext_vector_type(4))) float f32x4;

__device__ __forceinline__ unsigned short f2bf(float f) {
    __hip_bfloat16 h = __float2bfloat16(f);
    unsigned short u; __builtin_memcpy(&u, &h, 2); return u;
}

// ---------------------------------------------------------------------------
// N=32, 4096 px/sample (P=131072), D=512, K=116 (pad KP=128).
// Single-pass fusion: stream x ONCE per block (512 px), compute s=x*W with
// W k-slices in registers, cross-wave softmax, then ax^T += a^T * x from the
// SAME LDS x tile.  GEMM2's transposed x operand is built with plain
// ds_read_u16 gathers.  R2 bug fixed: aTs row stride was 40 (<64 p values)
// -> rows overlapped; now 72 (144 B, 16-B aligned rows).
//
// ws layout (bytes):
//   ax   @ 0        : 32*512*128*4 = 8,388,608  f32 (zeroed, atomic accum)
//   asum @ 8388608  : 32*128*4     = 16,384     f32 (zeroed)
//   ssb  @ 8404992  : 16,384                    f32 (zeroed)
//   scl  @ 8421376  : 16,384                    f32
//   WT   @ 8437760  : 128*512*2 = 131,072       bf16 (k,d), k>=116 zeroed
// ---------------------------------------------------------------------------

__global__ void wt_prep(const float* __restrict__ w,
                        unsigned short* __restrict__ WT) {
    int id = blockIdx.x * 256 + threadIdx.x;   // 65536 = 128*512
    int k = id >> 9, d = id & 511;
    WT[k * 512 + d] = (k < 116) ? f2bf(w[d * 116 + k]) : (unsigned short)0;
}

// 256 blocks: block = (n, 512-px chunk), 8 waves of 64.
// GEMM1: wave w owns k-slice [16w,16w+16), all 64 px of the tile, W in regs.
// GEMM2: wave w owns d-slice [64w,64w+64), all 128 k; acc2 = 128 VGPR.
__global__ __launch_bounds__(512, 2)
void fused_k(const float* __restrict__ x, const unsigned short* __restrict__ WT,
             float* __restrict__ ax, float* __restrict__ asum) {
    // xs: 64px x 512d bf16, subtiled [p/4][d/16][4][16] (strides 4096/128/32/2 B)
    __shared__ __align__(16) unsigned short xs[32768];     // 64 KiB
    __shared__ __align__(16) unsigned short aTs[128 * 72]; // aT (k,p) pad72, 18 KiB
    __shared__ __align__(16) float smax[64 * 12];          // per-px per-wave max
    __shared__ __align__(16) float ssum[64 * 12];          // per-px per-wave sum

    const int tid = threadIdx.x;
    const int wave = tid >> 6, lane = tid & 63;
    const int q = lane >> 4, l15 = lane & 15;
    const int n = blockIdx.x >> 3;
    const int pb = (blockIdx.x & 7) << 9;      // px base of this block
    const int kk = wave * 16 + l15;            // this lane's k (GEMM1 B col)
    const bool kvalid = kk < 116;

    // W^T k-slice -> registers: wt[kc] = WT[kk][kc*32 + q*8 .. +7]
    bf16x8 wt[16];
    {
        const unsigned short* wp = WT + (size_t)kk * 512 + q * 8;
#pragma unroll
        for (int kc = 0; kc < 16; ++kc) wt[kc] = *(const bf16x8*)(wp + kc * 32);
    }

    f32x4 acc2[8][4];                          // [kt][dt]: ax^T[k, d-slice]
#pragma unroll
    for (int a = 0; a < 8; ++a)
#pragma unroll
        for (int b = 0; b < 4; ++b) acc2[a][b] = (f32x4){0.f, 0.f, 0.f, 0.f};
    float asr = 0.f;                           // asum partial for k = kk

    // staging: this thread covers d = sd..sd+3 for px = (lane&3) + 4*j
    const int sd = wave * 64 + (lane >> 2) * 4;
    const float* xbase = x + (size_t)(n * 4096 + pb) * 512 + sd;
    const int wbase = (sd >> 4) * 128 + (lane & 3) * 32 + (sd & 15) * 2;

    for (int t = 0; t < 8; ++t) {
        // ---- stage 64-px tile: f32 -> bf16, subtiled, vectorized ----
        {
            const float* xt = xbase + (size_t)(t * 64 + (lane & 3)) * 512;
            float4 vb[8];
#pragma unroll
            for (int half = 0; half < 2; ++half) {
#pragma unroll
                for (int i = 0; i < 8; ++i)
                    vb[i] = *(const float4*)(xt + (size_t)(half * 8 + i) * 2048);
#pragma unroll
                for (int i = 0; i < 8; ++i) {
                    ushort4 u;
                    u.x = f2bf(vb[i].x); u.y = f2bf(vb[i].y);
                    u.z = f2bf(vb[i].z); u.w = f2bf(vb[i].w);
                    *(ushort4*)((char*)xs + wbase + (half * 8 + i) * 4096) = u;
                }
            }
        }
        __syncthreads();                       // B0: xs ready

        // ---- GEMM1: s[64 px x 16 k-slice], A from xs, B from regs ----
        f32x4 s1[4];
#pragma unroll
        for (int pt = 0; pt < 4; ++pt) s1[pt] = (f32x4){0.f, 0.f, 0.f, 0.f};
        {
            const int abase = (l15 >> 2) * 4096 + (l15 & 3) * 32 +
                              (q >> 1) * 128 + (q & 1) * 16;
#pragma unroll
            for (int kc = 0; kc < 16; ++kc)
#pragma unroll
                for (int pt = 0; pt < 4; ++pt) {
                    bf16x8 af = *(const bf16x8*)((char*)xs + abase +
                                                 pt * 16384 + kc * 256);
                    s1[pt] = __builtin_amdgcn_mfma_f32_16x16x32_bf16(
                        af, wt[kc], s1[pt], 0, 0, 0);
                }
        }

        // ---- softmax stage 1: per-px max over this wave's 16 k ----
        float mx[4][4];
#pragma unroll
        for (int pt = 0; pt < 4; ++pt)
#pragma unroll
            for (int r = 0; r < 4; ++r)
                mx[pt][r] = kvalid ? s1[pt][r] : -3.0e38f;
#pragma unroll
        for (int off = 1; off < 16; off <<= 1)
#pragma unroll
            for (int pt = 0; pt < 4; ++pt)
#pragma unroll
                for (int r = 0; r < 4; ++r)
                    mx[pt][r] = fmaxf(mx[pt][r], __shfl_xor(mx[pt][r], off));
        if (l15 == 0) {
#pragma unroll
            for (int pt = 0; pt < 4; ++pt)
#pragma unroll
                for (int r = 0; r < 4; ++r)
                    smax[(pt * 16 + q * 4 + r) * 12 + wave] = mx[pt][r];
        }
        __syncthreads();                       // B1: smax partials ready

        // ---- combine max over 8 waves, exp, local sums ----
        float sm[4][4];
#pragma unroll
        for (int pt = 0; pt < 4; ++pt)
#pragma unroll
            for (int r = 0; r < 4; ++r) {
                const float* mp = smax + (pt * 16 + q * 4 + r) * 12;
                f32x4 a0 = *(const f32x4*)mp;
                f32x4 b0 = *(const f32x4*)(mp + 4);
                float M = fmaxf(fmaxf(fmaxf(a0[0], a0[1]), fmaxf(a0[2], a0[3])),
                                fmaxf(fmaxf(b0[0], b0[1]), fmaxf(b0[2], b0[3])));
                float e0 = kvalid ? __expf(s1[pt][r] - M) : 0.f;
                s1[pt][r] = e0;
                sm[pt][r] = e0;
            }
#pragma unroll
        for (int off = 1; off < 16; off <<= 1)
#pragma unroll
            for (int pt = 0; pt < 4; ++pt)
#pragma unroll
                for (int r = 0; r < 4; ++r)
                    sm[pt][r] += __shfl_xor(sm[pt][r], off);
        if (l15 == 0) {
#pragma unroll
            for (int pt = 0; pt < 4; ++pt)
#pragma unroll
                for (int r = 0; r < 4; ++r)
                    ssum[(pt * 16 + q * 4 + r) * 12 + wave] = sm[pt][r];
        }
        __syncthreads();                       // B2: ssum partials ready

        // ---- normalize, write aT (row-major, pad 72), accumulate asum ----
#pragma unroll
        for (int pt = 0; pt < 4; ++pt) {
            float av[4];
#pragma unroll
            for (int r = 0; r < 4; ++r) {
                const float* sp = ssum + (pt * 16 + q * 4 + r) * 12;
                f32x4 a0 = *(const f32x4*)sp;
                f32x4 b0 = *(const f32x4*)(sp + 4);
                float S = (a0[0] + a0[1] + a0[2] + a0[3]) +
                          (b0[0] + b0[1] + b0[2] + b0[3]);
                av[r] = s1[pt][r] * (1.0f / S);
                asr += av[r];
            }
            ushort4 u;
            u.x = f2bf(av[0]); u.y = f2bf(av[1]);
            u.z = f2bf(av[2]); u.w = f2bf(av[3]);
            // aTs[k][p]: k=kk, p = pt*16 + q*4 + r
            *(ushort4*)(aTs + kk * 72 + pt * 16 + q * 4) = u;
        }
        __syncthreads();                       // B3: aT ready

        // ---- GEMM2: acc2[k, d-slice] += aT(k,p) * xs(p,d) over 64 p ----
#pragma unroll
        for (int pc = 0; pc < 2; ++pc) {
            // B-frags: x[p = pc*32 + q*8 + j][d = wave*64 + dt*16 + l15]
            // via 8 ds_read_u16 gathers from the subtiled p-major tile.
            bf16x8 Bv[4];
#pragma unroll
            for (int dt = 0; dt < 4; ++dt) {
                const int eb = (pc * 8 + q * 2) * 2048 + (wave * 4 + dt) * 64 + l15;
#pragma unroll
                for (int j = 0; j < 8; ++j)
                    Bv[dt][j] = (short)xs[eb + (j >> 2) * 2048 + (j & 3) * 16];
            }
#pragma unroll
            for (int kt = 0; kt < 8; ++kt) {
                bf16x8 A = *(const bf16x8*)(aTs + (kt * 16 + l15) * 72 +
                                            pc * 32 + q * 8);
#pragma unroll
                for (int dt = 0; dt < 4; ++dt)
                    acc2[kt][dt] = __builtin_amdgcn_mfma_f32_16x16x32_bf16(
                        A, Bv[dt], acc2[kt][dt], 0, 0, 0);
            }
        }
        __syncthreads();                       // B4: xs/aT consumed
    }

    // ---- epilogue: atomic-reduce acc2 into ax (n, d, k) ----
#pragma unroll
    for (int kt = 0; kt < 8; ++kt)
#pragma unroll
        for (int dt = 0; dt < 4; ++dt) {
            const int d = wave * 64 + dt * 16 + l15;
            float* pp = ax + ((size_t)(n * 512 + d) << 7) + kt * 16 + q * 4;
            atomicAdd(pp + 0, acc2[kt][dt][0]);
            atomicAdd(pp + 1, acc2[kt][dt][1]);
            atomicAdd(pp + 2, acc2[kt][dt][2]);
            atomicAdd(pp + 3, acc2[kt][dt][3]);
        }
    asr += __shfl_xor(asr, 16);
    asr += __shfl_xor(asr, 32);
    if (lane < 16 && kvalid) atomicAdd(asum + n * 128 + kk, asr);
}

// per-(n,k) sum over d of v^2, v = ax + C*asum ; partial over 64 d + atomic
__global__ void ss_k(const float* __restrict__ ax, const float* __restrict__ C,
                     const float* __restrict__ asum, float* __restrict__ ssb) {
    __shared__ float red[256];
    const int tid = threadIdx.x;
    const int n = blockIdx.x >> 3, dgrp = blockIdx.x & 7;
    const int k = tid & 127, dh = tid >> 7;
    const float as = asum[n * 128 + k];
    float ssq = 0.f;
    for (int i = 0; i < 32; ++i) {
        int d = dgrp * 64 + i * 2 + dh;
        size_t ix = (size_t)(n * 512 + d) * 128 + k;
        float cc = (k < 116) ? C[d * 116 + k] : 0.f;
        float v = ax[ix] + cc * as;
        ssq += v * v;
    }
    red[tid] = ssq;
    __syncthreads();
    if (dh == 0) atomicAdd(ssb + n * 128 + k, red[tid] + red[tid + 128]);
}

// combined scale = rsqrt(ss+eps) * rsqrt(sum_k ss/(ss+eps) + eps)
__global__ void scale_k(const float* __restrict__ ssb, float* __restrict__ scl) {
    __shared__ float red[128];
    const int n = blockIdx.x, k = threadIdx.x;
    const float s = ssb[n * 128 + k];
    red[k] = (k < 116) ? (s / (s + EPS_F)) : 0.f;
    __syncthreads();
    for (int off = 64; off > 0; off >>= 1) {
        if (k < off) red[k] += red[k + off];
        __syncthreads();
    }
    float rowinv = rsqrtf(red[0] + EPS_F);
    scl[n * 128 + k] = rsqrtf(s + EPS_F) * rowinv;
}

// out[n, d*116+k] = (ax + C*asum) * scale, fp32
__global__ void emit_k(const float* __restrict__ ax, const float* __restrict__ C,
                       const float* __restrict__ asum, const float* __restrict__ scl,
                       float* __restrict__ out) {
    const int n = blockIdx.x >> 3, dgrp = blockIdx.x & 7;
    const int tid = threadIdx.x;
    for (int i = 0; i < 29; ++i) {                // 29*256 = 7424 = 64*116
        int idx = i * 256 + tid;
        int dl = idx / 116;
        int k = idx - dl * 116;
        int d = dgrp * 64 + dl;
        size_t ix = (size_t)(n * 512 + d) * 128 + k;
        float v = ax[ix] + C[d * 116 + k] * asum[n * 128 + k];
        out[(size_t)n * 59392 + dgrp * 7424 + idx] = v * scl[n * 128 + k];
    }
}

extern "C" void kernel_launch(void* const* d_in, const int* in_sizes, int n_in,
                              void* d_out, int out_size, void* d_ws, size_t ws_size,
                              hipStream_t stream) {
    const float* x = (const float*)d_in[0];   // (32,64,64,512) f32
    const float* w = (const float*)d_in[1];   // (512,116) f32
    const float* C = (const float*)d_in[2];   // (512,116) f32
    float* out = (float*)d_out;               // (32, 59392) f32

    char* ws = (char*)d_ws;
    float* ax   = (float*)ws;
    float* asum = (float*)(ws + 8388608);
    float* ssb  = (float*)(ws + 8404992);
    float* scl  = (float*)(ws + 8421376);
    unsigned short* WT = (unsigned short*)(ws + 8437760);

    // zero ax + asum + ssb (contiguous 8,421,376 B); ws re-poisoned per call
    hipMemsetAsync(ws, 0, 8421376, stream);

    wt_prep<<<256, 256, 0, stream>>>(w, WT);
    fused_k<<<256, 512, 0, stream>>>(x, WT, ax, asum);
    ss_k   <<<256, 256, 0, stream>>>(ax, C, asum, ssb);
    scale_k<<<32, 128, 0, stream>>>(ssb, scl);
    emit_k <<<256, 256, 0, stream>>>(ax, C, asum, scl, out);
}